// Round 3
// baseline (1362.613 us; speedup 1.0000x reference)
//
#include <hip/hip_runtime.h>
#include <hip/hip_fp16.h>

typedef _Float16 f16x2 __attribute__((ext_vector_type(2)));
typedef _Float16 half8 __attribute__((ext_vector_type(8)));

#define TS  512
#define HID 256
#define G3  768
#define EMB 128
#define NB1 8
#define RPB 96   // rows per xi1-stage block
#define CTL 767  // poller/publisher thread
#define BSZ 8    // handshake batch (steps)

__device__ __forceinline__ float sigmoidf_(float x){ return 1.0f/(1.0f+__expf(-x)); }
__device__ __forceinline__ float tanhf_(float x){
  float e = __expf(-2.0f*fabsf(x));
  float t = (1.0f-e)/(1.0f+e);
  return copysignf(t,x);
}

// K1: xi0[t][j] = bih0[j] + sum_k Wih0[j][k] * emb[x[t,511]][k]
__global__ __launch_bounds__(256) void xi0_kernel(const int* __restrict__ x,
    const float* __restrict__ emb_tab, const float* __restrict__ Wih0,
    const float* __restrict__ bih0, float* __restrict__ xi0)
{
  __shared__ float embs[8][EMB];
  __shared__ int idx8[8];
  int tid = threadIdx.x;
  int t0  = blockIdx.x * 8;
  if (tid < 8) idx8[tid] = x[(t0 + tid)*512 + 511];
  __syncthreads();
  for (int i = tid; i < 8*EMB; i += 256){
    int q = i >> 7, r = i & 127;
    embs[q][r] = emb_tab[(long)idx8[q]*EMB + r];
  }
  __syncthreads();
  for (int g = 0; g < 3; g++){
    int j = g*256 + tid;
    float b = bih0[j];
    float acc[8];
    #pragma unroll
    for (int u=0;u<8;u++) acc[u]=b;
    const float4* wrow = (const float4*)(Wih0 + (long)j*EMB);
    #pragma unroll 8
    for (int m=0;m<EMB/4;m++){
      float4 w = wrow[m];
      #pragma unroll
      for (int u=0;u<8;u++){
        acc[u] += w.x*embs[u][4*m+0] + w.y*embs[u][4*m+1]
                + w.z*embs[u][4*m+2] + w.w*embs[u][4*m+3];
      }
    }
    #pragma unroll
    for (int u=0;u<8;u++) xi0[(long)(t0+u)*G3 + j] = acc[u];
  }
}

// ---------------- pipelined recurrence (1 kernel, 12 blocks) ----------------
// ROUND-16: rounds 13-15 proved the compiler will NEVER grant >84 VGPRs to
// this workgroup shape (launch_bounds min, waves_per_eu(3,3), and LDS-forced
// 1 wg/CU all no-ops on VGPR_Count=84). Full weight residency (128 regs)
// is therefore unreachable; measured 3350 cy/step == ~384 KB/step of weight
// state restreamed through one CU's L2 port (~128 B/cy). Structural fix:
// SPLIT each rec layer across TWO blocks by output-unit half. Each block:
// 384 weight rows -> 64 weight VGPRs/thread (demand ~94, spills ~10 regs,
// minor). Per-step h-half exchange through global memory using the
// already-proven release/acquire handshake (store -> __syncthreads (drains
// vmcnt) -> fence -> monotonic counter; partner: spin -> fence -> load).
// Pairs at (bid0,bid8)/(bid1,bid9) so round-robin XCD dispatch co-locates
// each pair on one XCD L2 (perf-only heuristic). xi1_stage polls the two
// layer-1 step counters (>= 8*(b+1)) instead of flagB.
// Predicted: pipe 725 -> ~260-380 us; step ~3350 -> ~1200-1500 cy.
#define SHUF(V,A,B) __builtin_shufflevector(V,V,A,B)
#define WR16(X) X(0,0) X(0,1) X(0,2) X(0,3) \
                X(1,0) X(1,1) X(1,2) X(1,3) \
                X(2,0) X(2,1) X(2,2) X(2,3) \
                X(3,0) X(3,1) X(3,2) X(3,3)

template<int MODE>  // 0 = layer-1 half-block, 1 = layer-2 half-block
__device__ __forceinline__ void rec_layer(const float* __restrict__ Whh,
    const float* __restrict__ bhh, const float* __restrict__ xi,
    _Float16* __restrict__ h16out, float* __restrict__ f32out,
    unsigned* __restrict__ cntB, unsigned* __restrict__ ctrOwn,
    unsigned* __restrict__ ctrPar, int P,
    _Float16 (*hbuf)[8*40], float* ghL, float* bhhL)
{
  int tid = threadIdx.x;
  int g   = tid >> 3;        // 0..95 : local rows 4g..4g+3 (of 384)
  int o   = tid & 7;         // col chunk [32o, 32o+32)
  const int BASE = P * 128;          // own h-unit base
  const int PB   = (1 - P) * 128;    // partner h-unit base

  // local row l (0..383) -> global weight row: gate = l>>7, unit = BASE+(l&127)
#define WDECL(I,C) half8 w##I##_##C;
  WR16(WDECL)
#define WLOAD(I,C) { \
    int l_ = 4*g + (I); \
    int wr_ = ((l_>>7)<<8) + BASE + (l_&127); \
    const float4* p_ = (const float4*)(Whh + (long)wr_*HID + 32*o + 8*(C)); \
    float4 u_ = p_[0], v_ = p_[1]; \
    w##I##_##C = (half8){(_Float16)u_.x,(_Float16)u_.y,(_Float16)u_.z,(_Float16)u_.w, \
                         (_Float16)v_.x,(_Float16)v_.y,(_Float16)v_.z,(_Float16)v_.w}; }
  WR16(WLOAD)

  float hprev = 0.f;
  float xr=0.f, xz=0.f, xn=0.f;
  if (tid < 384)
    bhhL[tid] = bhh[((tid>>7)<<8) + BASE + (tid&127)];
  if (tid < 80) ((half8*)hbuf)[tid] = (half8)(_Float16)0;  // zero both buffers

  if (MODE == 1 && tid == CTL){   // wait for batch 0 of xi1
    while (__hip_atomic_load(&cntB[0], __ATOMIC_RELAXED, __HIP_MEMORY_SCOPE_AGENT) < NB1)
      __builtin_amdgcn_s_sleep(1);
    __threadfence();
  }
  __syncthreads();
  if (tid < 128){  // xi for t=0 (MODE1: safe after cntB[0] confirmed)
    xr = xi[BASE+tid]; xz = xi[256+BASE+tid]; xn = xi[512+BASE+tid];
  }

  for (int t = 0; t < TS; t++){
    // consumer: at batch boundaries, confirm the NEXT xi1 batch so the
    // elementwise-phase prefetch of xi[t+1] is safe.
    if (MODE == 1 && tid == CTL && ((t+1) & (BSZ-1)) == 0 && t+1 < TS){
      unsigned b = (unsigned)(t+1) >> 3;
      while (__hip_atomic_load(&cntB[b], __ATOMIC_RELAXED, __HIP_MEMORY_SCOPE_AGENT) < NB1)
        __builtin_amdgcn_s_sleep(1);
      __threadfence();
    }

    // ---- partner-half fetch: h-state t (written by partner at its step t-1)
    if (t > 0 && tid < 64){
      while (__hip_atomic_load(ctrPar, __ATOMIC_RELAXED, __HIP_MEMORY_SCOPE_AGENT)
             < (unsigned)t) {}
      __threadfence();
      int u = PB + 2*tid;
      f16x2 v;
      if (MODE == 0){
        v = *(const f16x2*)(h16out + (long)(t-1)*HID + u);
      } else {
        float2 f = *(const float2*)(f32out + (long)(t-1)*HID + u);
        v.x = (_Float16)f.x; v.y = (_Float16)f.y;
      }
      *(f16x2*)(&hbuf[t & 1][(u>>5)*40 + (u&31)]) = v;
    }
    __syncthreads();

    // ---- dot phase: 4 h-chunk reads, 64 fdot2, accs a0..a3 ----
    const half8* hp = (const half8*)(&hbuf[t & 1][o*40]);
    float a0=0.f,a1=0.f,a2=0.f,a3=0.f;
#define DOT1(I,C,HV) \
    a##I = __builtin_amdgcn_fdot2(SHUF(w##I##_##C,0,1), SHUF(HV,0,1), a##I, false); \
    a##I = __builtin_amdgcn_fdot2(SHUF(w##I##_##C,2,3), SHUF(HV,2,3), a##I, false); \
    a##I = __builtin_amdgcn_fdot2(SHUF(w##I##_##C,4,5), SHUF(HV,4,5), a##I, false); \
    a##I = __builtin_amdgcn_fdot2(SHUF(w##I##_##C,6,7), SHUF(HV,6,7), a##I, false);
#define DOTCHUNK(C) { half8 hv = hp[C]; \
    DOT1(0,C,hv) DOT1(1,C,hv) DOT1(2,C,hv) DOT1(3,C,hv) }
    DOTCHUNK(0) DOTCHUNK(1) DOTCHUNK(2) DOTCHUNK(3)

    // ---- butterfly: 8 lanes x 4 rows -> lanes o<4 hold full dot of row 4g+o
    {
      bool b0 = o & 1, b1 = o & 2;
      float s, r_;
      s = b0 ? a0 : a1; r_ = __shfl_xor(s, 1, 64); float c0 = (b0 ? a1 : a0) + r_;
      s = b0 ? a2 : a3; r_ = __shfl_xor(s, 1, 64); float c1 = (b0 ? a3 : a2) + r_;
      s = b1 ? c0 : c1; r_ = __shfl_xor(s, 2, 64); float d  = (b1 ? c1 : c0) + r_;
      float e = d + __shfl_xor(d, 4, 64);
      if (o < 4) ghL[4*g + o] = e;
    }
    __syncthreads();

    // ---- elementwise phase: own units u = BASE + tid, tid < 128 ----
    if (tid < 128){
      float r = sigmoidf_(xr + bhhL[tid] + ghL[tid]);
      float z = sigmoidf_(xz + bhhL[128+tid] + ghL[128+tid]);
      float n = tanhf_(xn + r*(ghL[256+tid] + bhhL[256+tid]));
      float hnew = (1.0f - z)*n + z*hprev;
      hprev = hnew;
      float partner = __shfl_xor(hnew, 1, 64);
      int u = BASE + tid;
      if ((tid & 1) == 0){
        f16x2 p; p.x = (_Float16)hnew; p.y = (_Float16)partner;
        *(f16x2*)(&hbuf[(t+1)&1][(u>>5)*40 + (u&31)]) = p;
        if (MODE == 0){
          *(f16x2*)(h16out + (long)t*HID + u) = p;
        } else {
          float2 q; q.x = hnew; q.y = partner;
          *(float2*)(f32out + (long)t*HID + u) = q;
        }
      }
      if (t+1 < TS){  // prefetch xi[t+1]; latency rides under next dot phase
        const float* xp = xi + (long)(t+1)*G3;
        xr = xp[BASE+tid]; xz = xp[256+BASE+tid]; xn = xp[512+BASE+tid];
      }
    }
    __syncthreads();   // drains h stores (vmcnt) before publish
    if (tid == CTL){
      __threadfence();
      __hip_atomic_store(ctrOwn, (unsigned)(t+1), __ATOMIC_RELEASE, __HIP_MEMORY_SCOPE_AGENT);
    }
  }
}

__device__ __forceinline__ void xi1_stage(const float* __restrict__ Wih1,
    const float* __restrict__ bih1, const _Float16* __restrict__ h16,
    float* __restrict__ xi1, unsigned* __restrict__ ctrs,
    unsigned* __restrict__ cntB, int slice)
{
  int tid = threadIdx.x;
  int r = tid >> 3, o = tid & 7;        // row r of slice; cols [32o,32o+32)
  int row = slice*RPB + r;
  half8 w0,w1,w2,w3;                    // 16 VGPRs, register-resident slice
  {
    const float4* wp = (const float4*)(Wih1 + (long)row*HID + o*32);
    float4 p0=wp[0],p1=wp[1],p2=wp[2],p3=wp[3],p4=wp[4],p5=wp[5],p6=wp[6],p7=wp[7];
    w0 = (half8){(_Float16)p0.x,(_Float16)p0.y,(_Float16)p0.z,(_Float16)p0.w,
                 (_Float16)p1.x,(_Float16)p1.y,(_Float16)p1.z,(_Float16)p1.w};
    w1 = (half8){(_Float16)p2.x,(_Float16)p2.y,(_Float16)p2.z,(_Float16)p2.w,
                 (_Float16)p3.x,(_Float16)p3.y,(_Float16)p3.z,(_Float16)p3.w};
    w2 = (half8){(_Float16)p4.x,(_Float16)p4.y,(_Float16)p4.z,(_Float16)p4.w,
                 (_Float16)p5.x,(_Float16)p5.y,(_Float16)p5.z,(_Float16)p5.w};
    w3 = (half8){(_Float16)p6.x,(_Float16)p6.y,(_Float16)p6.z,(_Float16)p6.w,
                 (_Float16)p7.x,(_Float16)p7.y,(_Float16)p7.z,(_Float16)p7.w};
  }
  float bias = bih1[row];

  for (int b = 0; b < TS/BSZ; b++){
    if (tid == 0){
      unsigned tgt = (unsigned)(BSZ*(b+1));
      while (__hip_atomic_load(&ctrs[0],  __ATOMIC_RELAXED, __HIP_MEMORY_SCOPE_AGENT) < tgt ||
             __hip_atomic_load(&ctrs[16], __ATOMIC_RELAXED, __HIP_MEMORY_SCOPE_AGENT) < tgt)
        __builtin_amdgcn_s_sleep(1);
      __threadfence();
    }
    __syncthreads();
    #pragma unroll 4
    for (int u = 0; u < BSZ; u++){
      int t = b*BSZ + u;
      const half8* hp = (const half8*)(h16 + (long)t*HID + o*32);
      half8 h0 = hp[0], h1 = hp[1], h2 = hp[2], h3 = hp[3];
      float acc = 0.f;
#define XDOT(W,H) \
      acc = __builtin_amdgcn_fdot2(SHUF(W,0,1), SHUF(H,0,1), acc, false); \
      acc = __builtin_amdgcn_fdot2(SHUF(W,2,3), SHUF(H,2,3), acc, false); \
      acc = __builtin_amdgcn_fdot2(SHUF(W,4,5), SHUF(H,4,5), acc, false); \
      acc = __builtin_amdgcn_fdot2(SHUF(W,6,7), SHUF(H,6,7), acc, false);
      XDOT(w0,h0) XDOT(w1,h1) XDOT(w2,h2) XDOT(w3,h3)
      acc += __shfl_xor(acc, 1, 64);
      acc += __shfl_xor(acc, 2, 64);
      acc += __shfl_xor(acc, 4, 64);
      if (o == 0) xi1[(long)t*G3 + row] = acc + bias;
    }
    __syncthreads();   // drains each thread's stores (vmcnt) before fence
    if (tid == 0){
      __threadfence();
      atomicAdd(&cntB[b], 1u);
    }
  }
}

__global__ __launch_bounds__(768, 3)
void pipe_kernel(
    const float* __restrict__ Whh0, const float* __restrict__ bhh0,
    const float* __restrict__ xi0,
    const float* __restrict__ Wih1, const float* __restrict__ bih1,
    const float* __restrict__ Whh1, const float* __restrict__ bhh1,
    _Float16* __restrict__ h1f16, float* __restrict__ xi1,
    float* __restrict__ h2, unsigned* __restrict__ ctrs,
    unsigned* __restrict__ cntB)
{
  __shared__ __align__(16) _Float16 hbuf[2][8*40];
  __shared__ float ghL[384];
  __shared__ float bhhL[384];
  int bid = blockIdx.x;
  // counters: ctrs+0 = L1/P0, +16 = L1/P1, +32 = L2/P0, +48 = L2/P1 (64B apart)
  if (bid == 0)
    rec_layer<0>(Whh0, bhh0, xi0, h1f16, nullptr, cntB, ctrs+0,  ctrs+16, 0, hbuf, ghL, bhhL);
  else if (bid == 8)
    rec_layer<0>(Whh0, bhh0, xi0, h1f16, nullptr, cntB, ctrs+16, ctrs+0,  1, hbuf, ghL, bhhL);
  else if (bid == 1)
    rec_layer<1>(Whh1, bhh1, xi1, nullptr, h2,    cntB, ctrs+32, ctrs+48, 0, hbuf, ghL, bhhL);
  else if (bid == 9)
    rec_layer<1>(Whh1, bhh1, xi1, nullptr, h2,    cntB, ctrs+48, ctrs+32, 1, hbuf, ghL, bhhL);
  else {
    int slice = (bid < 8) ? bid - 2 : bid - 4;   // {2..7}->0..5, {10,11}->6,7
    xi1_stage(Wih1, bih1, h1f16, xi1, ctrs, cntB, slice);
  }
}

// K5: logits[t][c] = b_out[c] + sum_i h2[t][i] * W_out[c][i]
__global__ __launch_bounds__(1024) void logits_kernel(const float* __restrict__ h2,
    const float* __restrict__ Wout, const float* __restrict__ bout,
    float* __restrict__ out)
{
  __shared__ __align__(16) float wsm[2*HID];
  __shared__ float bs[2];
  int tid = threadIdx.x;
  if (tid < 2*HID) wsm[tid] = Wout[tid];
  if (tid < 2)     bs[tid]  = bout[tid];
  __syncthreads();
  int t = tid >> 1, c = tid & 1;
  const float4* hr = (const float4*)(h2 + (long)t*HID);
  const float4* wr = (const float4*)(wsm + c*HID);
  float acc = bs[c];
  #pragma unroll 8
  for (int m=0;m<HID/4;m++){
    float4 h = hr[m]; float4 wv = wr[m];
    acc += h.x*wv.x + h.y*wv.y + h.z*wv.z + h.w*wv.w;
  }
  out[tid] = acc;
}

extern "C" void kernel_launch(void* const* d_in, const int* in_sizes, int n_in,
                              void* d_out, int out_size, void* d_ws, size_t ws_size,
                              hipStream_t stream)
{
  const int*   x    = (const int*)  d_in[0];
  const float* emb  = (const float*)d_in[1];
  const float* Wih0 = (const float*)d_in[2];
  const float* Whh0 = (const float*)d_in[3];
  const float* bih0 = (const float*)d_in[4];
  const float* bhh0 = (const float*)d_in[5];
  const float* Wih1 = (const float*)d_in[6];
  const float* Whh1 = (const float*)d_in[7];
  const float* bih1 = (const float*)d_in[8];
  const float* bhh1 = (const float*)d_in[9];
  const float* Wout = (const float*)d_in[10];
  const float* bout = (const float*)d_in[11];
  float* out = (float*)d_out;

  char* ws = (char*)d_ws;
  float*     xi0   = (float*)(ws);                       // 512*768 f32 = 1.5 MB
  float*     xi1   = (float*)(ws + 1572864);             // 512*768 f32 = 1.5 MB
  _Float16*  h1f16 = (_Float16*)(ws + 3145728);          // 512*256 f16 = 256 KB
  float*     h2    = (float*)(ws + 3407872);             // 512*256 f32 = 512 KB
  unsigned*  ctrs  = (unsigned*)(ws + 3932160);          // 4 counters, 64B apart
  unsigned*  cntB  = (unsigned*)(ws + 3934208);          // 64 u32

  hipMemsetAsync(ws + 3932160, 0, 4096, stream);
  xi0_kernel<<<64, 256, 0, stream>>>(x, emb, Wih0, bih0, xi0);
  pipe_kernel<<<12, 768, 0, stream>>>(Whh0, bhh0, xi0, Wih1, bih1,
                                      Whh1, bhh1, h1f16, xi1, h2, ctrs, cntB);
  logits_kernel<<<1, 1024, 0, stream>>>(h2, Wout, bout, out);
}

// Round 4
// 1102.168 us; speedup vs baseline: 1.2363x; 1.2363x over previous
//
#include <hip/hip_runtime.h>
#include <hip/hip_fp16.h>

typedef _Float16 f16x2 __attribute__((ext_vector_type(2)));
typedef _Float16 half8 __attribute__((ext_vector_type(8)));

#define TS  512
#define HID 256
#define G3  768
#define EMB 128
#define NB1 8
#define RPB 96   // rows per xi1-stage block
#define CTL 767  // poller/publisher thread
#define BSZ 8    // handshake batch (steps)

__device__ __forceinline__ float sigmoidf_(float x){ return 1.0f/(1.0f+__expf(-x)); }
__device__ __forceinline__ float tanhf_(float x){
  float e = __expf(-2.0f*fabsf(x));
  float t = (1.0f-e)/(1.0f+e);
  return copysignf(t,x);
}

// K1: xi0[t][j] = bih0[j] + sum_k Wih0[j][k] * emb[x[t,511]][k]
__global__ __launch_bounds__(256) void xi0_kernel(const int* __restrict__ x,
    const float* __restrict__ emb_tab, const float* __restrict__ Wih0,
    const float* __restrict__ bih0, float* __restrict__ xi0)
{
  __shared__ float embs[8][EMB];
  __shared__ int idx8[8];
  int tid = threadIdx.x;
  int t0  = blockIdx.x * 8;
  if (tid < 8) idx8[tid] = x[(t0 + tid)*512 + 511];
  __syncthreads();
  for (int i = tid; i < 8*EMB; i += 256){
    int q = i >> 7, r = i & 127;
    embs[q][r] = emb_tab[(long)idx8[q]*EMB + r];
  }
  __syncthreads();
  for (int g = 0; g < 3; g++){
    int j = g*256 + tid;
    float b = bih0[j];
    float acc[8];
    #pragma unroll
    for (int u=0;u<8;u++) acc[u]=b;
    const float4* wrow = (const float4*)(Wih0 + (long)j*EMB);
    #pragma unroll 8
    for (int m=0;m<EMB/4;m++){
      float4 w = wrow[m];
      #pragma unroll
      for (int u=0;u<8;u++){
        acc[u] += w.x*embs[u][4*m+0] + w.y*embs[u][4*m+1]
                + w.z*embs[u][4*m+2] + w.w*embs[u][4*m+3];
      }
    }
    #pragma unroll
    for (int u=0;u<8;u++) xi0[(long)(t0+u)*G3 + j] = acc[u];
  }
}

// ---------------- pipelined recurrence (1 kernel, 10 blocks) ----------------
// ROUND-17: single-block structure restored (round-16's two-block split
// regressed to 6050 cy/step: per-step cross-CU handshake ~2.7k cy).
// Rounds 13-15 proved the arch-VGPR grant (~84) is an internal pressure
// heuristic immune to all attributes; streaming weights is walled at
// ~3200 cy/step by the CU's L1/L2 port (measured 3350). Fix: bypass the
// allocator. Pin 20 of the 32 weight-half8s (80 dwords/thread) in AGPRs
// via inline-asm v_accvgpr_write/read ("a" constraints, volatile so reads
// can't be hoisted back into arch pressure). Arch keeps 12 half8 (48 regs)
// + working ~26 = demand ~74 <= 84 -> spill-free. Total ~84+80 = 164 <= 170
// -> 3 waves/SIMD -> the 12-wave workgroup still fits.
// Swap: -2600 cy spill reload, +480 cy accvgpr reads (80/thread/step).
// Predicted: step ~3350 -> ~1500-1700 cy; pipe 725 -> ~300-400 us.
#define SHUF(V,A,B) __builtin_shufflevector(V,V,A,B)
// arch-resident slots (I = row 0..2 of each 8-row group)
#define WRA(X) X(0,0) X(0,1) X(0,2) X(0,3) \
               X(1,0) X(1,1) X(1,2) X(1,3) \
               X(2,0) X(2,1) X(2,2) X(2,3)
// AGPR-resident slots (I = 3..7)
#define WRG(X) X(3,0) X(3,1) X(3,2) X(3,3) X(4,0) X(4,1) X(4,2) X(4,3) \
               X(5,0) X(5,1) X(5,2) X(5,3) X(6,0) X(6,1) X(6,2) X(6,3) \
               X(7,0) X(7,1) X(7,2) X(7,3)

template<int MODE>  // 0 = producer (layer 1), 1 = consumer (layer 2)
__device__ __forceinline__ void rec_layer(const float* __restrict__ Whh,
    const float* __restrict__ bhh, const float* __restrict__ xi,
    _Float16* __restrict__ h16out, float* __restrict__ f32out,
    unsigned* __restrict__ flagB, unsigned* __restrict__ cntB,
    _Float16 (*hbuf)[8*40], float* gh, float* bhhL)
{
  int tid = threadIdx.x;
  int g   = tid >> 3;        // 0..95 : rows 8g..8g+7
  int o   = tid & 7;         // col chunk [32o, 32o+32)

#define WDECL(I,C) half8 w##I##_##C;
  WRA(WDECL)
#define GDECL(I,C) float q##I##_##C##_0, q##I##_##C##_1, q##I##_##C##_2, q##I##_##C##_3;
  WRG(GDECL)

#define WLOAD(I,C) { \
    const float4* p_ = (const float4*)(Whh + (long)(8*g+(I))*HID + 32*o + 8*(C)); \
    float4 u_ = p_[0], v_ = p_[1]; \
    w##I##_##C = (half8){(_Float16)u_.x,(_Float16)u_.y,(_Float16)u_.z,(_Float16)u_.w, \
                         (_Float16)v_.x,(_Float16)v_.y,(_Float16)v_.z,(_Float16)v_.w}; }
  WRA(WLOAD)
#define GLOAD(I,C) { \
    const float4* p_ = (const float4*)(Whh + (long)(8*g+(I))*HID + 32*o + 8*(C)); \
    float4 u_ = p_[0], v_ = p_[1]; \
    f16x2 t_; \
    t_.x = (_Float16)u_.x; t_.y = (_Float16)u_.y; \
    asm volatile("v_accvgpr_write_b32 %0, %1" : "=a"(q##I##_##C##_0) : "v"(__builtin_bit_cast(float, t_))); \
    t_.x = (_Float16)u_.z; t_.y = (_Float16)u_.w; \
    asm volatile("v_accvgpr_write_b32 %0, %1" : "=a"(q##I##_##C##_1) : "v"(__builtin_bit_cast(float, t_))); \
    t_.x = (_Float16)v_.x; t_.y = (_Float16)v_.y; \
    asm volatile("v_accvgpr_write_b32 %0, %1" : "=a"(q##I##_##C##_2) : "v"(__builtin_bit_cast(float, t_))); \
    t_.x = (_Float16)v_.z; t_.y = (_Float16)v_.w; \
    asm volatile("v_accvgpr_write_b32 %0, %1" : "=a"(q##I##_##C##_3) : "v"(__builtin_bit_cast(float, t_))); }
  WRG(GLOAD)

  float hprev = 0.f;
  float xr=0.f, xz=0.f, xn=0.f;
  bhhL[tid] = bhh[tid];                       // biases live in LDS
  if (tid < 80) ((half8*)hbuf)[tid] = (half8)(_Float16)0;  // zero both buffers

  if (MODE == 1 && tid == CTL){   // wait for batch 0 of xi1
    while (__hip_atomic_load(&cntB[0], __ATOMIC_RELAXED, __HIP_MEMORY_SCOPE_AGENT) < NB1)
      __builtin_amdgcn_s_sleep(1);
    __threadfence();
  }
  __syncthreads();
  if (tid < HID){  // xi for t=0 (MODE1: safe after cntB[0] confirmed)
    xr = xi[tid]; xz = xi[HID+tid]; xn = xi[2*HID+tid];
  }

  for (int t = 0; t < TS; t++){
    // consumer: at the last step of a batch, confirm the NEXT batch so the
    // elementwise-phase prefetch of xi[t+1] is safe.
    if (MODE == 1 && tid == CTL && ((t+1) & (BSZ-1)) == 0 && t+1 < TS){
      unsigned b = (unsigned)(t+1) >> 3;
      while (__hip_atomic_load(&cntB[b], __ATOMIC_RELAXED, __HIP_MEMORY_SCOPE_AGENT) < NB1)
        __builtin_amdgcn_s_sleep(1);
      __threadfence();
    }

    // ---- dot phase: 4 h-chunk reads, 128 fdot2, accs a0..a7 ----
    const half8* hp = (const half8*)(&hbuf[t & 1][o*40]);
    float a0=0.f,a1=0.f,a2=0.f,a3=0.f,a4=0.f,a5=0.f,a6=0.f,a7=0.f;
#define DOT1(I,C,HV) \
    a##I = __builtin_amdgcn_fdot2(SHUF(w##I##_##C,0,1), SHUF(HV,0,1), a##I, false); \
    a##I = __builtin_amdgcn_fdot2(SHUF(w##I##_##C,2,3), SHUF(HV,2,3), a##I, false); \
    a##I = __builtin_amdgcn_fdot2(SHUF(w##I##_##C,4,5), SHUF(HV,4,5), a##I, false); \
    a##I = __builtin_amdgcn_fdot2(SHUF(w##I##_##C,6,7), SHUF(HV,6,7), a##I, false);
#define GDOT(I,C,HV) { float t_; \
    asm volatile("v_accvgpr_read_b32 %0, %1" : "=v"(t_) : "a"(q##I##_##C##_0)); \
    a##I = __builtin_amdgcn_fdot2(__builtin_bit_cast(f16x2, t_), SHUF(HV,0,1), a##I, false); \
    asm volatile("v_accvgpr_read_b32 %0, %1" : "=v"(t_) : "a"(q##I##_##C##_1)); \
    a##I = __builtin_amdgcn_fdot2(__builtin_bit_cast(f16x2, t_), SHUF(HV,2,3), a##I, false); \
    asm volatile("v_accvgpr_read_b32 %0, %1" : "=v"(t_) : "a"(q##I##_##C##_2)); \
    a##I = __builtin_amdgcn_fdot2(__builtin_bit_cast(f16x2, t_), SHUF(HV,4,5), a##I, false); \
    asm volatile("v_accvgpr_read_b32 %0, %1" : "=v"(t_) : "a"(q##I##_##C##_3)); \
    a##I = __builtin_amdgcn_fdot2(__builtin_bit_cast(f16x2, t_), SHUF(HV,6,7), a##I, false); }
#define DOTCHUNK(C) { half8 hv = hp[C]; \
    DOT1(0,C,hv) DOT1(1,C,hv) DOT1(2,C,hv) \
    GDOT(3,C,hv) GDOT(4,C,hv) GDOT(5,C,hv) GDOT(6,C,hv) GDOT(7,C,hv) }
    DOTCHUNK(0) DOTCHUNK(1) DOTCHUNK(2) DOTCHUNK(3)

    // ---- 8-lane butterfly; lane o ends with full dot of row 8g+o == tid ----
    bool b0 = o & 1, b1 = o & 2, b2 = o & 4;
    float s, r_;
    s = b0 ? a0 : a1; r_ = __shfl_xor(s, 1, 64); float c0 = (b0 ? a1 : a0) + r_;
    s = b0 ? a2 : a3; r_ = __shfl_xor(s, 1, 64); float c1 = (b0 ? a3 : a2) + r_;
    s = b0 ? a4 : a5; r_ = __shfl_xor(s, 1, 64); float c2 = (b0 ? a5 : a4) + r_;
    s = b0 ? a6 : a7; r_ = __shfl_xor(s, 1, 64); float c3 = (b0 ? a7 : a6) + r_;
    s = b1 ? c0 : c1; r_ = __shfl_xor(s, 2, 64); float d0 = (b1 ? c1 : c0) + r_;
    s = b1 ? c2 : c3; r_ = __shfl_xor(s, 2, 64); float d1 = (b1 ? c3 : c2) + r_;
    s = b2 ? d0 : d1; r_ = __shfl_xor(s, 4, 64); float e  = (b2 ? d1 : d0) + r_;
    gh[tid] = e;
    __syncthreads();

    // ---- elementwise phase: unit j = tid < 256 ----
    if (tid < HID){
      float r = sigmoidf_(xr + bhhL[tid] + gh[tid]);
      float z = sigmoidf_(xz + bhhL[HID+tid] + gh[HID+tid]);
      float n = tanhf_(xn + r*(gh[2*HID+tid] + bhhL[2*HID+tid]));
      float hnew = (1.0f - z)*n + z*hprev;
      hprev = hnew;
      if (MODE == 1) f32out[(long)t*HID + tid] = hnew;
      float partner = __shfl_xor(hnew, 1, 64);
      if ((tid & 1) == 0){
        f16x2 p; p.x = (_Float16)hnew; p.y = (_Float16)partner;
        *(f16x2*)(&hbuf[(t+1)&1][(tid>>5)*40 + (tid&31)]) = p;
        if (MODE == 0) *(f16x2*)(h16out + (long)t*HID + tid) = p;
      }
      if (t+1 < TS){  // prefetch xi[t+1]; latency rides under next dot phase
        const float* xp = xi + (long)(t+1)*G3;
        xr = xp[tid]; xz = xp[HID+tid]; xn = xp[2*HID+tid];
      }
    }
    __syncthreads();
    // producer: publish once per batch
    if (MODE == 0 && tid == CTL && ((t+1) & (BSZ-1)) == 0){
      __threadfence();
      __hip_atomic_store(&flagB[t >> 3], 1u, __ATOMIC_RELEASE, __HIP_MEMORY_SCOPE_AGENT);
    }
  }
}

__device__ __forceinline__ void xi1_stage(const float* __restrict__ Wih1,
    const float* __restrict__ bih1, const _Float16* __restrict__ h16,
    float* __restrict__ xi1, unsigned* __restrict__ flagB,
    unsigned* __restrict__ cntB, int slice)
{
  int tid = threadIdx.x;
  int r = tid >> 3, o = tid & 7;        // row r of slice; cols [32o,32o+32)
  int row = slice*RPB + r;
  half8 w0,w1,w2,w3;                    // 16 VGPRs, register-resident slice
  {
    const float4* wp = (const float4*)(Wih1 + (long)row*HID + o*32);
    float4 p0=wp[0],p1=wp[1],p2=wp[2],p3=wp[3],p4=wp[4],p5=wp[5],p6=wp[6],p7=wp[7];
    w0 = (half8){(_Float16)p0.x,(_Float16)p0.y,(_Float16)p0.z,(_Float16)p0.w,
                 (_Float16)p1.x,(_Float16)p1.y,(_Float16)p1.z,(_Float16)p1.w};
    w1 = (half8){(_Float16)p2.x,(_Float16)p2.y,(_Float16)p2.z,(_Float16)p2.w,
                 (_Float16)p3.x,(_Float16)p3.y,(_Float16)p3.z,(_Float16)p3.w};
    w2 = (half8){(_Float16)p4.x,(_Float16)p4.y,(_Float16)p4.z,(_Float16)p4.w,
                 (_Float16)p5.x,(_Float16)p5.y,(_Float16)p5.z,(_Float16)p5.w};
    w3 = (half8){(_Float16)p6.x,(_Float16)p6.y,(_Float16)p6.z,(_Float16)p6.w,
                 (_Float16)p7.x,(_Float16)p7.y,(_Float16)p7.z,(_Float16)p7.w};
  }
  float bias = bih1[row];

  for (int b = 0; b < TS/BSZ; b++){
    if (tid == 0){
      while (__hip_atomic_load(&flagB[b], __ATOMIC_RELAXED, __HIP_MEMORY_SCOPE_AGENT) == 0u)
        __builtin_amdgcn_s_sleep(1);
      __threadfence();
    }
    __syncthreads();
    #pragma unroll 4
    for (int u = 0; u < BSZ; u++){
      int t = b*BSZ + u;
      const half8* hp = (const half8*)(h16 + (long)t*HID + o*32);
      half8 h0 = hp[0], h1 = hp[1], h2 = hp[2], h3 = hp[3];
      float acc = 0.f;
#define XDOT(W,H) \
      acc = __builtin_amdgcn_fdot2(SHUF(W,0,1), SHUF(H,0,1), acc, false); \
      acc = __builtin_amdgcn_fdot2(SHUF(W,2,3), SHUF(H,2,3), acc, false); \
      acc = __builtin_amdgcn_fdot2(SHUF(W,4,5), SHUF(H,4,5), acc, false); \
      acc = __builtin_amdgcn_fdot2(SHUF(W,6,7), SHUF(H,6,7), acc, false);
      XDOT(w0,h0) XDOT(w1,h1) XDOT(w2,h2) XDOT(w3,h3)
      acc += __shfl_xor(acc, 1, 64);
      acc += __shfl_xor(acc, 2, 64);
      acc += __shfl_xor(acc, 4, 64);
      if (o == 0) xi1[(long)t*G3 + row] = acc + bias;
    }
    __syncthreads();   // drains each thread's stores (vmcnt) before fence
    if (tid == 0){
      __threadfence();
      atomicAdd(&cntB[b], 1u);
    }
  }
}

__global__ __launch_bounds__(768, 3)
void pipe_kernel(
    const float* __restrict__ Whh0, const float* __restrict__ bhh0,
    const float* __restrict__ xi0,
    const float* __restrict__ Wih1, const float* __restrict__ bih1,
    const float* __restrict__ Whh1, const float* __restrict__ bhh1,
    _Float16* __restrict__ h1f16, float* __restrict__ xi1,
    float* __restrict__ h2, unsigned* __restrict__ flagB,
    unsigned* __restrict__ cntB)
{
  __shared__ __align__(16) _Float16 hbuf[2][8*40];
  __shared__ float gh[G3];
  __shared__ float bhhL[G3];
  int bid = blockIdx.x;
  if (bid == 0)
    rec_layer<0>(Whh0, bhh0, xi0, h1f16, nullptr, flagB, cntB, hbuf, gh, bhhL);
  else if (bid == 9)
    rec_layer<1>(Whh1, bhh1, xi1, nullptr, h2, flagB, cntB, hbuf, gh, bhhL);
  else
    xi1_stage(Wih1, bih1, h1f16, xi1, flagB, cntB, bid - 1);
}

// K5: logits[t][c] = b_out[c] + sum_i h2[t][i] * W_out[c][i]
__global__ __launch_bounds__(1024) void logits_kernel(const float* __restrict__ h2,
    const float* __restrict__ Wout, const float* __restrict__ bout,
    float* __restrict__ out)
{
  __shared__ __align__(16) float wsm[2*HID];
  __shared__ float bs[2];
  int tid = threadIdx.x;
  if (tid < 2*HID) wsm[tid] = Wout[tid];
  if (tid < 2)     bs[tid]  = bout[tid];
  __syncthreads();
  int t = tid >> 1, c = tid & 1;
  const float4* hr = (const float4*)(h2 + (long)t*HID);
  const float4* wr = (const float4*)(wsm + c*HID);
  float acc = bs[c];
  #pragma unroll 8
  for (int m=0;m<HID/4;m++){
    float4 h = hr[m]; float4 wv = wr[m];
    acc += h.x*wv.x + h.y*wv.y + h.z*wv.z + h.w*wv.w;
  }
  out[tid] = acc;
}

extern "C" void kernel_launch(void* const* d_in, const int* in_sizes, int n_in,
                              void* d_out, int out_size, void* d_ws, size_t ws_size,
                              hipStream_t stream)
{
  const int*   x    = (const int*)  d_in[0];
  const float* emb  = (const float*)d_in[1];
  const float* Wih0 = (const float*)d_in[2];
  const float* Whh0 = (const float*)d_in[3];
  const float* bih0 = (const float*)d_in[4];
  const float* bhh0 = (const float*)d_in[5];
  const float* Wih1 = (const float*)d_in[6];
  const float* Whh1 = (const float*)d_in[7];
  const float* bih1 = (const float*)d_in[8];
  const float* bhh1 = (const float*)d_in[9];
  const float* Wout = (const float*)d_in[10];
  const float* bout = (const float*)d_in[11];
  float* out = (float*)d_out;

  char* ws = (char*)d_ws;
  float*     xi0   = (float*)(ws);                       // 512*768 f32 = 1.5 MB
  float*     xi1   = (float*)(ws + 1572864);             // 512*768 f32 = 1.5 MB
  _Float16*  h1f16 = (_Float16*)(ws + 3145728);          // 512*256 f16 = 256 KB
  float*     h2    = (float*)(ws + 3407872);             // 512*256 f32 = 512 KB
  unsigned*  flagB = (unsigned*)(ws + 3932160);          // 64 u32
  unsigned*  cntB  = (unsigned*)(ws + 3934208);          // 64 u32

  hipMemsetAsync(ws + 3932160, 0, 4096, stream);
  xi0_kernel<<<64, 256, 0, stream>>>(x, emb, Wih0, bih0, xi0);
  pipe_kernel<<<10, 768, 0, stream>>>(Whh0, bhh0, xi0, Wih1, bih1,
                                      Whh1, bhh1, h1f16, xi1, h2, flagB, cntB);
  logits_kernel<<<1, 1024, 0, stream>>>(h2, Wout, bout, out);
}

// Round 5
// 893.682 us; speedup vs baseline: 1.5247x; 1.2333x over previous
//
#include <hip/hip_runtime.h>
#include <hip/hip_fp16.h>

typedef _Float16 f16x2 __attribute__((ext_vector_type(2)));
typedef _Float16 half8 __attribute__((ext_vector_type(8)));

#define TS  512
#define HID 256
#define G3  768
#define EMB 128
#define THR 512   // threads per pipe block
#define NB1 12    // xi1 producer blocks
#define RPB 64    // rows per xi1-stage block
#define CTL 511   // poller/publisher thread
#define BSZ 8     // handshake batch (steps)

__device__ __forceinline__ float sigmoidf_(float x){ return 1.0f/(1.0f+__expf(-x)); }
__device__ __forceinline__ float tanhf_(float x){
  float e = __expf(-2.0f*fabsf(x));
  float t = (1.0f-e)/(1.0f+e);
  return copysignf(t,x);
}

// K1: xi0[t][j] = bih0[j] + sum_k Wih0[j][k] * emb[x[t,511]][k]
// + packs the L2-streamed weight rows (I=9..11 of each 12-row group) to f16.
__global__ __launch_bounds__(256) void xi0_kernel(const int* __restrict__ x,
    const float* __restrict__ emb_tab, const float* __restrict__ Wih0,
    const float* __restrict__ bih0, float* __restrict__ xi0,
    const float* __restrict__ Whh0, const float* __restrict__ Whh1,
    _Float16* __restrict__ wpk0, _Float16* __restrict__ wpk1)
{
  __shared__ float embs[8][EMB];
  __shared__ int idx8[8];
  int tid = threadIdx.x;
  int t0  = blockIdx.x * 8;
  if (tid < 8) idx8[tid] = x[(t0 + tid)*512 + 511];
  __syncthreads();
  for (int i = tid; i < 8*EMB; i += 256){
    int q = i >> 7, r = i & 127;
    embs[q][r] = emb_tab[(long)idx8[q]*EMB + r];
  }
  __syncthreads();
  for (int g = 0; g < 3; g++){
    int j = g*256 + tid;
    float b = bih0[j];
    float acc[8];
    #pragma unroll
    for (int u=0;u<8;u++) acc[u]=b;
    const float4* wrow = (const float4*)(Wih0 + (long)j*EMB);
    #pragma unroll 8
    for (int m=0;m<EMB/4;m++){
      float4 w = wrow[m];
      #pragma unroll
      for (int u=0;u<8;u++){
        acc[u] += w.x*embs[u][4*m+0] + w.y*embs[u][4*m+1]
                + w.z*embs[u][4*m+2] + w.w*embs[u][4*m+3];
      }
    }
    #pragma unroll
    for (int u=0;u<8;u++) xi0[(long)(t0+u)*G3 + j] = acc[u];
  }
  // ---- pack streamed rows: s in [0,192): row = 12*(s/3) + 9 + s%3 ----
  int gid = blockIdx.x*256 + tid;
  for (int e = gid; e < 2*192*256; e += 64*256){
    int L = (e >= 192*256) ? 1 : 0;
    int i = e - L*192*256;
    int s = i >> 8, c = i & 255;
    int row = 12*(s/3) + 9 + (s%3);
    const float* W = L ? Whh1 : Whh0;
    _Float16*    P = L ? wpk1 : wpk0;
    P[i] = (_Float16)W[(long)row*HID + c];
  }
}

// ---------------- pipelined recurrence (1 kernel, 14 blocks) ----------------
// ROUND-18: rounds 13-17 establish: (a) arch-VGPR grant is ~capped (84 @768thr)
// and immune to attributes/LDS/AGPR pinning (gfx950 unified file!); (b) cross-CU
// per-step handshake ~2.7k cy (r16); (c) the 3350 cy/step wall = weight state
// restreamed through scratch/L2 at ~100 B/cy. New design: accept the cap, feed
// the dot phase from THREE CONCURRENT sources. 512-thr rec blocks (grant should
// scale to ~512/4=128 regs), 64 groups x 8 lanes, 12 rows/group:
//   rows 0-5  -> registers (24 half8 = 96 dw/thread)
//   rows 6-8  -> LDS, thread-private layout ldsw[k*512+tid] (98 KB, zero
//                bank conflicts: lanes stride 16B)   ~1150 cy/step @85 B/cy
//   rows 9-11 -> streamed from L2 as packed f16 (98 KB/step ~1000 cy)
// Paths overlap each other and ~1120 cy of VALU issue -> step ~1400-1600 cy.
// Tells: VGPR_Count ~128?; LDS_Block_Size ~106K; pipe 732 -> ~300-480 us.
#define SHUF(V,A,B) __builtin_shufflevector(V,V,A,B)
#define WR24(X) X(0,0) X(0,1) X(0,2) X(0,3) X(1,0) X(1,1) X(1,2) X(1,3) \
                X(2,0) X(2,1) X(2,2) X(2,3) X(3,0) X(3,1) X(3,2) X(3,3) \
                X(4,0) X(4,1) X(4,2) X(4,3) X(5,0) X(5,1) X(5,2) X(5,3)

template<int MODE>  // 0 = producer (layer 1), 1 = consumer (layer 2)
__device__ __forceinline__ void rec_layer(const float* __restrict__ Whh,
    const float* __restrict__ bhh, const float* __restrict__ xi,
    const _Float16* __restrict__ wpk,
    _Float16* __restrict__ h16out, float* __restrict__ f32out,
    unsigned* __restrict__ flagB, unsigned* __restrict__ cntB,
    _Float16 (*hbuf)[8*40], half8* ldsw, float* gh, float* bhhL)
{
  int tid = threadIdx.x;
  int g   = tid >> 3;        // 0..63 : rows 12g..12g+11
  int o   = tid & 7;         // col chunk [32o, 32o+32)

#define WDECL(I,C) half8 w##I##_##C;
  WR24(WDECL)
#define WLOAD(I,C) { \
    const float4* p_ = (const float4*)(Whh + (long)(12*g+(I))*HID + 32*o + 8*(C)); \
    float4 u_ = p_[0], v_ = p_[1]; \
    w##I##_##C = (half8){(_Float16)u_.x,(_Float16)u_.y,(_Float16)u_.z,(_Float16)u_.w, \
                         (_Float16)v_.x,(_Float16)v_.y,(_Float16)v_.z,(_Float16)v_.w}; }
  WR24(WLOAD)

  // LDS rows I=6..8 (12 half8/thread), thread-private conflict-free layout
  #pragma unroll
  for (int k = 0; k < 12; k++){
    int row = 12*g + 6 + (k >> 2);
    int C = k & 3;
    const float4* p_ = (const float4*)(Whh + (long)row*HID + 32*o + 8*C);
    float4 u_ = p_[0], v_ = p_[1];
    ldsw[k*THR + tid] = (half8){(_Float16)u_.x,(_Float16)u_.y,(_Float16)u_.z,(_Float16)u_.w,
                                (_Float16)v_.x,(_Float16)v_.y,(_Float16)v_.z,(_Float16)v_.w};
  }
  // streamed rows I=9..11 base pointers (packed f16, row s = 3g+j)
  const half8* sp0 = (const half8*)(wpk + ((long)(3*g+0))*HID + 32*o);
  const half8* sp1 = (const half8*)(wpk + ((long)(3*g+1))*HID + 32*o);
  const half8* sp2 = (const half8*)(wpk + ((long)(3*g+2))*HID + 32*o);

  float hprev = 0.f;
  float xr=0.f, xz=0.f, xn=0.f;
  for (int i = tid; i < G3; i += THR) bhhL[i] = bhh[i];
  if (tid < 80) ((half8*)hbuf)[tid] = (half8)(_Float16)0;  // zero both buffers

  if (MODE == 1 && tid == CTL){   // wait for batch 0 of xi1
    while (__hip_atomic_load(&cntB[0], __ATOMIC_RELAXED, __HIP_MEMORY_SCOPE_AGENT) < NB1)
      __builtin_amdgcn_s_sleep(1);
    __threadfence();
  }
  __syncthreads();
  if (tid < HID){  // xi for t=0 (MODE1: safe after cntB[0] confirmed)
    xr = xi[tid]; xz = xi[HID+tid]; xn = xi[2*HID+tid];
  }

  for (int t = 0; t < TS; t++){
    // consumer: at batch boundaries confirm the NEXT batch so the
    // elementwise-phase prefetch of xi[t+1] is safe.
    if (MODE == 1 && tid == CTL && ((t+1) & (BSZ-1)) == 0 && t+1 < TS){
      unsigned b = (unsigned)(t+1) >> 3;
      while (__hip_atomic_load(&cntB[b], __ATOMIC_RELAXED, __HIP_MEMORY_SCOPE_AGENT) < NB1)
        __builtin_amdgcn_s_sleep(1);
      __threadfence();
    }

    // ---- dot phase: 12 rows/thread from regs + LDS + L2 stream ----
    const half8* hp = (const half8*)(&hbuf[t & 1][o*40]);
    float a0=0.f,a1=0.f,a2=0.f,a3=0.f,a4=0.f,a5=0.f,
          a6=0.f,a7=0.f,a8=0.f,a9=0.f,a10=0.f,a11=0.f;
#define D8(ACC, WV, HV) \
    ACC = __builtin_amdgcn_fdot2(SHUF(WV,0,1), SHUF(HV,0,1), ACC, false); \
    ACC = __builtin_amdgcn_fdot2(SHUF(WV,2,3), SHUF(HV,2,3), ACC, false); \
    ACC = __builtin_amdgcn_fdot2(SHUF(WV,4,5), SHUF(HV,4,5), ACC, false); \
    ACC = __builtin_amdgcn_fdot2(SHUF(WV,6,7), SHUF(HV,6,7), ACC, false);
#define CHUNK(C) { half8 hv = hp[C]; \
    half8 l0 = ldsw[(0*4+(C))*THR + tid]; \
    half8 l1 = ldsw[(1*4+(C))*THR + tid]; \
    half8 l2 = ldsw[(2*4+(C))*THR + tid]; \
    half8 s0 = sp0[C]; half8 s1 = sp1[C]; half8 s2 = sp2[C]; \
    D8(a0, w0_##C, hv) D8(a1, w1_##C, hv) D8(a2, w2_##C, hv) \
    D8(a3, w3_##C, hv) D8(a4, w4_##C, hv) D8(a5, w5_##C, hv) \
    D8(a6, l0, hv) D8(a7, l1, hv) D8(a8, l2, hv) \
    D8(a9, s0, hv) D8(a10, s1, hv) D8(a11, s2, hv) }
    CHUNK(0) CHUNK(1) CHUNK(2) CHUNK(3)

    // ---- butterfly: rows 0..7 (8-tree), rows 8..11 (4-tree) ----
    bool b0 = o & 1, b1 = o & 2, b2 = o & 4;
    float s, r_;
    s = b0 ? a0 : a1; r_ = __shfl_xor(s, 1, 64); float c0 = (b0 ? a1 : a0) + r_;
    s = b0 ? a2 : a3; r_ = __shfl_xor(s, 1, 64); float c1 = (b0 ? a3 : a2) + r_;
    s = b0 ? a4 : a5; r_ = __shfl_xor(s, 1, 64); float c2 = (b0 ? a5 : a4) + r_;
    s = b0 ? a6 : a7; r_ = __shfl_xor(s, 1, 64); float c3 = (b0 ? a7 : a6) + r_;
    s = b1 ? c0 : c1; r_ = __shfl_xor(s, 2, 64); float d0 = (b1 ? c1 : c0) + r_;
    s = b1 ? c2 : c3; r_ = __shfl_xor(s, 2, 64); float d1 = (b1 ? c3 : c2) + r_;
    s = b2 ? d0 : d1; r_ = __shfl_xor(s, 4, 64); float e  = (b2 ? d1 : d0) + r_;
    gh[12*g + o] = e;
    s = b0 ? a8 : a9;   r_ = __shfl_xor(s, 1, 64); float c4 = (b0 ? a9  : a8 ) + r_;
    s = b0 ? a10 : a11; r_ = __shfl_xor(s, 1, 64); float c5 = (b0 ? a11 : a10) + r_;
    s = b1 ? c4 : c5;   r_ = __shfl_xor(s, 2, 64); float d2 = (b1 ? c5  : c4 ) + r_;
    float e2 = d2 + __shfl_xor(d2, 4, 64);
    if (o < 4) gh[12*g + 8 + o] = e2;
    __syncthreads();

    // ---- elementwise phase: unit j = tid < 256 ----
    if (tid < HID){
      float r = sigmoidf_(xr + bhhL[tid] + gh[tid]);
      float z = sigmoidf_(xz + bhhL[HID+tid] + gh[HID+tid]);
      float n = tanhf_(xn + r*(gh[2*HID+tid] + bhhL[2*HID+tid]));
      float hnew = (1.0f - z)*n + z*hprev;
      hprev = hnew;
      if (MODE == 1) f32out[(long)t*HID + tid] = hnew;
      float partner = __shfl_xor(hnew, 1, 64);
      if ((tid & 1) == 0){
        f16x2 p; p.x = (_Float16)hnew; p.y = (_Float16)partner;
        *(f16x2*)(&hbuf[(t+1)&1][(tid>>5)*40 + (tid&31)]) = p;
        if (MODE == 0) *(f16x2*)(h16out + (long)t*HID + tid) = p;
      }
      if (t+1 < TS){  // prefetch xi[t+1]; latency rides under next dot phase
        const float* xp = xi + (long)(t+1)*G3;
        xr = xp[tid]; xz = xp[HID+tid]; xn = xp[2*HID+tid];
      }
    }
    __syncthreads();   // drains h stores (vmcnt) before publish
    // producer: publish once per batch
    if (MODE == 0 && tid == CTL && ((t+1) & (BSZ-1)) == 0){
      __threadfence();
      __hip_atomic_store(&flagB[t >> 3], 1u, __ATOMIC_RELEASE, __HIP_MEMORY_SCOPE_AGENT);
    }
  }
}

__device__ __forceinline__ void xi1_stage(const float* __restrict__ Wih1,
    const float* __restrict__ bih1, const _Float16* __restrict__ h16,
    float* __restrict__ xi1, unsigned* __restrict__ flagB,
    unsigned* __restrict__ cntB, int slice)
{
  int tid = threadIdx.x;
  int r = tid >> 3, o = tid & 7;        // row r of slice; cols [32o,32o+32)
  int row = slice*RPB + r;
  half8 w0,w1,w2,w3;                    // 16 VGPRs, register-resident slice
  {
    const float4* wp = (const float4*)(Wih1 + (long)row*HID + o*32);
    float4 p0=wp[0],p1=wp[1],p2=wp[2],p3=wp[3],p4=wp[4],p5=wp[5],p6=wp[6],p7=wp[7];
    w0 = (half8){(_Float16)p0.x,(_Float16)p0.y,(_Float16)p0.z,(_Float16)p0.w,
                 (_Float16)p1.x,(_Float16)p1.y,(_Float16)p1.z,(_Float16)p1.w};
    w1 = (half8){(_Float16)p2.x,(_Float16)p2.y,(_Float16)p2.z,(_Float16)p2.w,
                 (_Float16)p3.x,(_Float16)p3.y,(_Float16)p3.z,(_Float16)p3.w};
    w2 = (half8){(_Float16)p4.x,(_Float16)p4.y,(_Float16)p4.z,(_Float16)p4.w,
                 (_Float16)p5.x,(_Float16)p5.y,(_Float16)p5.z,(_Float16)p5.w};
    w3 = (half8){(_Float16)p6.x,(_Float16)p6.y,(_Float16)p6.z,(_Float16)p6.w,
                 (_Float16)p7.x,(_Float16)p7.y,(_Float16)p7.z,(_Float16)p7.w};
  }
  float bias = bih1[row];

  for (int b = 0; b < TS/BSZ; b++){
    if (tid == 0){
      while (__hip_atomic_load(&flagB[b], __ATOMIC_RELAXED, __HIP_MEMORY_SCOPE_AGENT) == 0u)
        __builtin_amdgcn_s_sleep(1);
      __threadfence();
    }
    __syncthreads();
    #pragma unroll 4
    for (int u = 0; u < BSZ; u++){
      int t = b*BSZ + u;
      const half8* hp = (const half8*)(h16 + (long)t*HID + o*32);
      half8 h0 = hp[0], h1 = hp[1], h2 = hp[2], h3 = hp[3];
      float acc = 0.f;
#define XDOT(W,H) \
      acc = __builtin_amdgcn_fdot2(SHUF(W,0,1), SHUF(H,0,1), acc, false); \
      acc = __builtin_amdgcn_fdot2(SHUF(W,2,3), SHUF(H,2,3), acc, false); \
      acc = __builtin_amdgcn_fdot2(SHUF(W,4,5), SHUF(H,4,5), acc, false); \
      acc = __builtin_amdgcn_fdot2(SHUF(W,6,7), SHUF(H,6,7), acc, false);
      XDOT(w0,h0) XDOT(w1,h1) XDOT(w2,h2) XDOT(w3,h3)
      acc += __shfl_xor(acc, 1, 64);
      acc += __shfl_xor(acc, 2, 64);
      acc += __shfl_xor(acc, 4, 64);
      if (o == 0) xi1[(long)t*G3 + row] = acc + bias;
    }
    __syncthreads();   // drains each thread's stores (vmcnt) before fence
    if (tid == 0){
      __threadfence();
      atomicAdd(&cntB[b], 1u);
    }
  }
}

__global__ __launch_bounds__(THR, 2)
void pipe_kernel(
    const float* __restrict__ Whh0, const float* __restrict__ bhh0,
    const float* __restrict__ xi0,
    const float* __restrict__ Wih1, const float* __restrict__ bih1,
    const float* __restrict__ Whh1, const float* __restrict__ bhh1,
    const _Float16* __restrict__ wpk0, const _Float16* __restrict__ wpk1,
    _Float16* __restrict__ h1f16, float* __restrict__ xi1,
    float* __restrict__ h2, unsigned* __restrict__ flagB,
    unsigned* __restrict__ cntB)
{
  __shared__ __align__(16) half8 ldsw[12*THR];         // 98304 B
  __shared__ __align__(16) _Float16 hbuf[2][8*40];     // 1280 B
  __shared__ float gh[G3];                             // 3072 B
  __shared__ float bhhL[G3];                           // 3072 B
  int bid = blockIdx.x;
  if (bid == 0)
    rec_layer<0>(Whh0, bhh0, xi0, wpk0, h1f16, nullptr, flagB, cntB, hbuf, ldsw, gh, bhhL);
  else if (bid == 13)
    rec_layer<1>(Whh1, bhh1, xi1, wpk1, nullptr, h2, flagB, cntB, hbuf, ldsw, gh, bhhL);
  else
    xi1_stage(Wih1, bih1, h1f16, xi1, flagB, cntB, bid - 1);
}

// K5: logits[t][c] = b_out[c] + sum_i h2[t][i] * W_out[c][i]
__global__ __launch_bounds__(1024) void logits_kernel(const float* __restrict__ h2,
    const float* __restrict__ Wout, const float* __restrict__ bout,
    float* __restrict__ out)
{
  __shared__ __align__(16) float wsm[2*HID];
  __shared__ float bs[2];
  int tid = threadIdx.x;
  if (tid < 2*HID) wsm[tid] = Wout[tid];
  if (tid < 2)     bs[tid]  = bout[tid];
  __syncthreads();
  int t = tid >> 1, c = tid & 1;
  const float4* hr = (const float4*)(h2 + (long)t*HID);
  const float4* wr = (const float4*)(wsm + c*HID);
  float acc = bs[c];
  #pragma unroll 8
  for (int m=0;m<HID/4;m++){
    float4 h = hr[m]; float4 wv = wr[m];
    acc += h.x*wv.x + h.y*wv.y + h.z*wv.z + h.w*wv.w;
  }
  out[tid] = acc;
}

extern "C" void kernel_launch(void* const* d_in, const int* in_sizes, int n_in,
                              void* d_out, int out_size, void* d_ws, size_t ws_size,
                              hipStream_t stream)
{
  const int*   x    = (const int*)  d_in[0];
  const float* emb  = (const float*)d_in[1];
  const float* Wih0 = (const float*)d_in[2];
  const float* Whh0 = (const float*)d_in[3];
  const float* bih0 = (const float*)d_in[4];
  const float* bhh0 = (const float*)d_in[5];
  const float* Wih1 = (const float*)d_in[6];
  const float* Whh1 = (const float*)d_in[7];
  const float* bih1 = (const float*)d_in[8];
  const float* bhh1 = (const float*)d_in[9];
  const float* Wout = (const float*)d_in[10];
  const float* bout = (const float*)d_in[11];
  float* out = (float*)d_out;

  char* ws = (char*)d_ws;
  float*     xi0   = (float*)(ws);                       // 512*768 f32 = 1.5 MB
  float*     xi1   = (float*)(ws + 1572864);             // 512*768 f32 = 1.5 MB
  _Float16*  h1f16 = (_Float16*)(ws + 3145728);          // 512*256 f16 = 256 KB
  float*     h2    = (float*)(ws + 3407872);             // 512*256 f32 = 512 KB
  unsigned*  flagB = (unsigned*)(ws + 3932160);          // 64 u32
  unsigned*  cntB  = (unsigned*)(ws + 3934208);          // 64 u32
  _Float16*  wpk0  = (_Float16*)(ws + 3936256);          // 192*256 f16 = 96 KB
  _Float16*  wpk1  = (_Float16*)(ws + 4034560);          // 192*256 f16 = 96 KB

  hipMemsetAsync(ws + 3932160, 0, 4096, stream);
  xi0_kernel<<<64, 256, 0, stream>>>(x, emb, Wih0, bih0, xi0,
                                     Whh0, Whh1, wpk0, wpk1);
  pipe_kernel<<<14, THR, 0, stream>>>(Whh0, bhh0, xi0, Wih1, bih1,
                                      Whh1, bhh1, wpk0, wpk1,
                                      h1f16, xi1, h2, flagB, cntB);
  logits_kernel<<<1, 1024, 0, stream>>>(h2, Wout, bout, out);
}